// Round 1
// baseline (1750.366 us; speedup 1.0000x reference)
//
#include <hip/hip_runtime.h>
#include <hip/hip_bf16.h>

#define NN 256
#define NH 8
#define NB 4
#define NPOS (NB * NN * NN)   // 262144 positions (b,n,m)

// ---------------------------------------------------------------------------
// Kernel 1: attn[p][h] = sigmoid( dot(concat(q[p],k[p]), W[:,h]) + b[h] )
// One wave per position. lane = g*8 + h: g = d-chunk (64 floats), h = head.
// W chunk (64 coeffs) lives in registers; Q/K rows read as float4 (coalesced
// within each 8-lane broadcast group). 3-step shfl_xor reduces over g.
// ---------------------------------------------------------------------------
__global__ __launch_bounds__(256) void attn_kernel(
    const float* __restrict__ q, const float* __restrict__ k,
    const float* __restrict__ W, const float* __restrict__ bias,
    float* __restrict__ attn)
{
    const int lane = threadIdx.x & 63;
    const int h = lane & 7;
    const int g = lane >> 3;           // 0..7 : which 64-float chunk of ft[512]
    const int gwave = blockIdx.x * (blockDim.x >> 6) + (threadIdx.x >> 6);
    const int nwaves = gridDim.x * (blockDim.x >> 6);

    // preload W rows [g*64 .. g*64+63], column h into registers
    float wreg[64];
#pragma unroll
    for (int j = 0; j < 64; ++j)
        wreg[j] = W[(size_t)((g << 6) + j) * NH + h];
    const float bb = bias[h];

    const float* base = (g < 4) ? q : k;      // ft = [q | k]
    const size_t chunkOff = (size_t)(g & 3) * 64;

    for (int p = gwave; p < NPOS; p += nwaves) {
        const float* src = base + (size_t)p * 256 + chunkOff;
        float acc = 0.f;
#pragma unroll
        for (int j = 0; j < 16; ++j) {
            float4 v = *reinterpret_cast<const float4*>(src + j * 4);
            acc += v.x * wreg[4 * j + 0];
            acc += v.y * wreg[4 * j + 1];
            acc += v.z * wreg[4 * j + 2];
            acc += v.w * wreg[4 * j + 3];
        }
        // reduce over g (lanes differing in bits 3..5)
        acc += __shfl_xor(acc, 8);
        acc += __shfl_xor(acc, 16);
        acc += __shfl_xor(acc, 32);
        if (lane < 8) {
            float s = 1.f / (1.f + __expf(-(acc + bb)));
            attn[(size_t)p * NH + lane] = s;
        }
    }
}

// ---------------------------------------------------------------------------
// Kernel 2: dim2_mask union of top-k / bottom-k indices.
// Task t in [0,16384): variant = t>>13 (0: attn*m1, kt=64,kb=64;
//                                       1: attn*m2, kt=128,kb=64)
// row r = t&8191 -> (b,n,h). Element m (thread id) value a[m].
// v selected in top-k  iff  #{u: a[u]>a[v]} + #{u<v: a[u]==a[v]} < kt
// v selected in bot-k  iff  #{u: a[u]<a[v]} + #{u<v: a[u]==a[v]} < kb
// (matches jax.lax.top_k stable tie-breaking on a and on -a)
// Mask bits are monotonic 0->1: once all 256 set, set done flag, blocks skip.
// ---------------------------------------------------------------------------
__global__ __launch_bounds__(256) void topk_kernel(
    const float* __restrict__ attn, const float* __restrict__ m1,
    const float* __restrict__ m2, unsigned int* __restrict__ maskw,
    int* __restrict__ done)
{
    __shared__ float a[NN];
    __shared__ int sdone;
    const int tid = threadIdx.x;
    const int T = 2 * NB * NN * NH;   // 16384 tasks

    for (int t = blockIdx.x; t < T; t += gridDim.x) {
        if (tid == 0) sdone = atomicAdd(done, 0);
        __syncthreads();               // also protects 'a' reuse across iters
        if (sdone) continue;

        const int variant = t >> 13;
        const int r = t & 8191;
        const int h = r & 7;
        const int n = (r >> 3) & 255;
        const int b = r >> 11;
        const size_t rowBase = ((size_t)(b * NN + n)) * NN;
        const float* mk = variant ? m2 : m1;
        const int kt = variant ? 128 : 64;
        const int kb = 64;

        a[tid] = attn[(rowBase + tid) * NH + h] * mk[rowBase + tid];
        __syncthreads();

        const float av = a[tid];
        int gt = 0, lt = 0, el = 0;
#pragma unroll 8
        for (int u = 0; u < NN; ++u) {
            const float au = a[u];     // same address across wave: broadcast
            gt += (au > av);
            lt += (au < av);
            el += (au == av) & (u < tid);
        }
        const bool sel = ((gt + el) < kt) || ((lt + el) < kb);
        if (sel) atomicOr(&maskw[tid >> 5], 1u << (tid & 31));
        __syncthreads();

        if (tid == 0) {
            bool all = true;
#pragma unroll
            for (int i = 0; i < 8; ++i)
                all = all && (atomicOr(&maskw[i], 0u) == 0xFFFFFFFFu);
            if (all) atomicExch(done, 1);
        }
    }
}

// ---------------------------------------------------------------------------
// Kernel 3: out *= (m1+m2) * dim2_mask[m], in place, float4 over H.
// ---------------------------------------------------------------------------
__global__ __launch_bounds__(256) void finalize_kernel(
    float* __restrict__ out, const float* __restrict__ m1,
    const float* __restrict__ m2, const unsigned int* __restrict__ maskw)
{
    const int total = NPOS * 2;       // float4 units (H=8 -> 2 per position)
    for (int i4 = blockIdx.x * blockDim.x + threadIdx.x; i4 < total;
         i4 += gridDim.x * blockDim.x) {
        const int m = (i4 >> 1) & 255;
        const int bn = i4 >> 9;
        const float bit =
            ((maskw[m >> 5] >> (m & 31)) & 1u) ? 1.f : 0.f;
        const size_t mi = (size_t)bn * NN + m;
        const float scale = (m1[mi] + m2[mi]) * bit;
        float4 v = reinterpret_cast<float4*>(out)[i4];
        v.x *= scale; v.y *= scale; v.z *= scale; v.w *= scale;
        reinterpret_cast<float4*>(out)[i4] = v;
    }
}

__global__ void init_kernel(unsigned int* maskw, int* done)
{
    if (threadIdx.x < 8) maskw[threadIdx.x] = 0u;
    if (threadIdx.x == 8) *done = 0;
}

extern "C" void kernel_launch(void* const* d_in, const int* in_sizes, int n_in,
                              void* d_out, int out_size, void* d_ws, size_t ws_size,
                              hipStream_t stream) {
    const float* q    = (const float*)d_in[0];
    const float* kk   = (const float*)d_in[1];
    const float* m1   = (const float*)d_in[2];
    const float* m2   = (const float*)d_in[3];
    const float* W    = (const float*)d_in[4];
    const float* bias = (const float*)d_in[5];
    float* out = (float*)d_out;

    unsigned int* maskw = (unsigned int*)d_ws;
    int* done = (int*)((char*)d_ws + 32);

    hipLaunchKernelGGL(init_kernel, dim3(1), dim3(64), 0, stream, maskw, done);
    hipLaunchKernelGGL(attn_kernel, dim3(4096), dim3(256), 0, stream,
                       q, kk, W, bias, out);
    hipLaunchKernelGGL(topk_kernel, dim3(1024), dim3(256), 0, stream,
                       out, m1, m2, maskw, done);
    hipLaunchKernelGGL(finalize_kernel, dim3(2048), dim3(256), 0, stream,
                       out, m1, m2, maskw);
}

// Round 3
// 384.565 us; speedup vs baseline: 4.5515x; 4.5515x over previous
//
#include <hip/hip_runtime.h>
#include <hip/hip_bf16.h>

#define NN 256
#define NH 8
#define NB 4
#define NPOS (NB * NN * NN)   // 262144 positions (b,n,m)

typedef float f32x4 __attribute__((ext_vector_type(4)));

// ---------------------------------------------------------------------------
// Kernel 1: attn[p][h] = sigmoid( dot(concat(q[p],k[p]), W[:,h]) + b[h] )
// One wave per 2 positions per iteration (ILP). lane = g*8 + h: g = d-chunk
// (64 floats), h = head. W chunk (64 coeffs) in registers; nontemporal f32x4
// loads (Q/K are stream-once). 3-step shfl_xor reduce over g.
// ---------------------------------------------------------------------------
__global__ __launch_bounds__(256) void attn_kernel(
    const float* __restrict__ q, const float* __restrict__ k,
    const float* __restrict__ W, const float* __restrict__ bias,
    float* __restrict__ attn)
{
    const int lane = threadIdx.x & 63;
    const int h = lane & 7;
    const int g = lane >> 3;           // 0..7 : which 64-float chunk of ft[512]
    const int gwave = blockIdx.x * (blockDim.x >> 6) + (threadIdx.x >> 6);
    const int nwaves = gridDim.x * (blockDim.x >> 6);   // 16384

    float wreg[64];
#pragma unroll
    for (int j = 0; j < 64; ++j)
        wreg[j] = W[(size_t)((g << 6) + j) * NH + h];
    const float bb = bias[h];

    const float* base = (g < 4) ? q : k;      // ft = [q | k]
    const size_t chunkOff = (size_t)(g & 3) * 64;

    // NPOS % (2*nwaves) == 0 for the launch below
    for (int p = gwave * 2; p < NPOS; p += nwaves * 2) {
        const f32x4* src0 = reinterpret_cast<const f32x4*>(base + (size_t)p * 256 + chunkOff);
        const f32x4* src1 = reinterpret_cast<const f32x4*>(base + (size_t)(p + 1) * 256 + chunkOff);
        float acc0 = 0.f, acc1 = 0.f;
#pragma unroll
        for (int j = 0; j < 16; ++j) {
            f32x4 v0 = __builtin_nontemporal_load(src0 + j);
            f32x4 v1 = __builtin_nontemporal_load(src1 + j);
            acc0 += v0.x * wreg[4 * j + 0];
            acc0 += v0.y * wreg[4 * j + 1];
            acc0 += v0.z * wreg[4 * j + 2];
            acc0 += v0.w * wreg[4 * j + 3];
            acc1 += v1.x * wreg[4 * j + 0];
            acc1 += v1.y * wreg[4 * j + 1];
            acc1 += v1.z * wreg[4 * j + 2];
            acc1 += v1.w * wreg[4 * j + 3];
        }
        acc0 += __shfl_xor(acc0, 8);
        acc0 += __shfl_xor(acc0, 16);
        acc0 += __shfl_xor(acc0, 32);
        acc1 += __shfl_xor(acc1, 8);
        acc1 += __shfl_xor(acc1, 16);
        acc1 += __shfl_xor(acc1, 32);
        if (lane < 8) {
            attn[(size_t)p * NH + lane]        = 1.f / (1.f + __expf(-(acc0 + bb)));
            attn[(size_t)(p + 1) * NH + lane]  = 1.f / (1.f + __expf(-(acc1 + bb)));
        }
    }
}

// ---------------------------------------------------------------------------
// Kernel 2: dim2_mask union of top-k / bottom-k indices (exact rank count,
// matches jax.lax.top_k stable tie-breaking).
// Per-thread selection bit (bit = tid = m) accumulated in a REGISTER across
// tasks; published once via ballot + 2 atomicOr per wave. 64 publisher blocks
// publish per-task to seed the global mask; everyone early-exits on a full
// mask via plain volatile loads (bits are monotonic 0->1, so a stale read
// under-reports only; a seen-full mask is truly full => skipping publish is
// a semantic no-op).
// ---------------------------------------------------------------------------
__global__ __launch_bounds__(256) void topk_kernel(
    const float* __restrict__ attn, const float* __restrict__ m1,
    const float* __restrict__ m2, unsigned int* __restrict__ maskw)
{
    __shared__ __align__(16) float a[NN];
    __shared__ int snotfull;
    const int tid = threadIdx.x;
    const int T = 2 * NB * NN * NH;   // 16384 tasks
    const bool publisher = (blockIdx.x < 64);
    const volatile unsigned int* vmask = maskw;
    bool selAcc = false;
    bool broke = false;

    for (int t = blockIdx.x; t < T; t += gridDim.x) {
        if (t != (int)blockIdx.x) {     // early-exit check (not before task 1)
            if (tid == 0) snotfull = 0;
            __syncthreads();
            if (tid < 8 && vmask[tid] != 0xFFFFFFFFu) snotfull = 1;
            __syncthreads();
            if (!snotfull) { broke = true; break; }
        }

        const int variant = t >> 13;
        const int r = t & 8191;
        const int h = r & 7;
        const int n = (r >> 3) & 255;
        const int b = r >> 11;
        const size_t rowBase = ((size_t)(b * NN + n)) * NN;
        const float* mk = variant ? m2 : m1;
        const int kt = variant ? 128 : 64;
        const int kb = 64;

        a[tid] = attn[(rowBase + tid) * NH + h] * mk[rowBase + tid];
        __syncthreads();

        const float av = a[tid];
        int gt = 0, lt = 0, el = 0;
#pragma unroll 8
        for (int u4 = 0; u4 < NN / 4; ++u4) {
            const f32x4 w = *reinterpret_cast<const f32x4*>(&a[u4 * 4]); // LDS b128 broadcast
            const int u = u4 * 4;
            gt += (w.x > av) + (w.y > av) + (w.z > av) + (w.w > av);
            lt += (w.x < av) + (w.y < av) + (w.z < av) + (w.w < av);
            el += ((w.x == av) & (u + 0 < tid)) + ((w.y == av) & (u + 1 < tid))
                + ((w.z == av) & (u + 2 < tid)) + ((w.w == av) & (u + 3 < tid));
        }
        const bool sel = ((gt + el) < kt) || ((lt + el) < kb);
        selAcc |= sel;

        if (publisher) {
            const unsigned long long bal = __ballot(sel);
            if ((tid & 63) == 0) {
                const int w = tid >> 6;
                atomicOr(&maskw[w * 2 + 0], (unsigned int)(bal & 0xFFFFFFFFull));
                atomicOr(&maskw[w * 2 + 1], (unsigned int)(bal >> 32));
            }
        }
        __syncthreads();   // protect a[] reuse next iteration
    }

    if (!broke && !publisher) {
        const unsigned long long bal = __ballot(selAcc);
        if ((tid & 63) == 0) {
            const int w = tid >> 6;
            atomicOr(&maskw[w * 2 + 0], (unsigned int)(bal & 0xFFFFFFFFull));
            atomicOr(&maskw[w * 2 + 1], (unsigned int)(bal >> 32));
        }
    }
}

// ---------------------------------------------------------------------------
// Kernel 3: out *= (m1+m2) * dim2_mask[m], in place, float4 over H.
// ---------------------------------------------------------------------------
__global__ __launch_bounds__(256) void finalize_kernel(
    float* __restrict__ out, const float* __restrict__ m1,
    const float* __restrict__ m2, const unsigned int* __restrict__ maskw)
{
    const int total = NPOS * 2;       // float4 units (H=8 -> 2 per position)
    for (int i4 = blockIdx.x * blockDim.x + threadIdx.x; i4 < total;
         i4 += gridDim.x * blockDim.x) {
        const int m = (i4 >> 1) & 255;
        const int bn = i4 >> 9;
        const float bit = ((maskw[m >> 5] >> (m & 31)) & 1u) ? 1.f : 0.f;
        const size_t mi = (size_t)bn * NN + m;
        const float scale = (m1[mi] + m2[mi]) * bit;
        f32x4 v = reinterpret_cast<f32x4*>(out)[i4];
        v.x *= scale; v.y *= scale; v.z *= scale; v.w *= scale;
        reinterpret_cast<f32x4*>(out)[i4] = v;
    }
}

__global__ void init_kernel(unsigned int* maskw)
{
    if (threadIdx.x < 8) maskw[threadIdx.x] = 0u;
}

extern "C" void kernel_launch(void* const* d_in, const int* in_sizes, int n_in,
                              void* d_out, int out_size, void* d_ws, size_t ws_size,
                              hipStream_t stream) {
    const float* q    = (const float*)d_in[0];
    const float* kk   = (const float*)d_in[1];
    const float* m1   = (const float*)d_in[2];
    const float* m2   = (const float*)d_in[3];
    const float* W    = (const float*)d_in[4];
    const float* bias = (const float*)d_in[5];
    float* out = (float*)d_out;

    unsigned int* maskw = (unsigned int*)d_ws;

    hipLaunchKernelGGL(init_kernel, dim3(1), dim3(64), 0, stream, maskw);
    hipLaunchKernelGGL(attn_kernel, dim3(4096), dim3(256), 0, stream,
                       q, kk, W, bias, out);
    hipLaunchKernelGGL(topk_kernel, dim3(1024), dim3(256), 0, stream,
                       out, m1, m2, maskw);
    hipLaunchKernelGGL(finalize_kernel, dim3(2048), dim3(256), 0, stream,
                       out, m1, m2, maskw);
}

// Round 4
// 232.964 us; speedup vs baseline: 7.5135x; 1.6508x over previous
//
#include <hip/hip_runtime.h>
#include <hip/hip_bf16.h>

#define NN 256
#define NH 8
#define NB 4
#define NPOS (NB * NN * NN)   // 262144 positions (b,n,m)

typedef float f32x4 __attribute__((ext_vector_type(4)));

__device__ __forceinline__ void stage16(const float* gsrc, char* ldst) {
    __builtin_amdgcn_global_load_lds(
        (const __attribute__((address_space(1))) void*)gsrc,
        (__attribute__((address_space(3))) void*)ldst,
        16, 0, 0);   // 16B per lane: lane i -> ldst + 16*i  (1KB per inst)
}

// ---------------------------------------------------------------------------
// Kernel 1: attn[p][h] = sigmoid( dot(concat(q[p],k[p]), W[:,h]) + b[h] )
// Wave-private LDS double buffer (8KB/wave), staged via global_load_lds
// (fully coalesced 1KB/inst, counted vmcnt -- no __syncthreads, no cross-wave
// sharing). lane=(g,h): g = 64-float chunk of ft[512], h = head.
// LDS reads XOR-swizzled (step s reads element s^g) -> 8 distinct bank-quads,
// zero conflicts; W coefficients pre-permuted so wreg index is compile-time.
// ---------------------------------------------------------------------------
__global__ __launch_bounds__(256, 4) void attn_kernel(
    const float* __restrict__ q, const float* __restrict__ k,
    const float* __restrict__ W, const float* __restrict__ bias,
    float* __restrict__ attn)
{
    __shared__ __align__(256) char lds[32768];   // 4 waves x 2 buf x 4KB
    const int tid = threadIdx.x;
    const int lane = tid & 63;
    const int wid = tid >> 6;
    const int h = lane & 7;
    const int g = lane >> 3;          // 0..7

    // wreg[4*s+c] = W coeff for data element e = s^g of this lane's chunk
    float wreg[64];
#pragma unroll
    for (int s = 0; s < 16; ++s) {
        const int e = s ^ g;          // s<16, g<8 -> e<16
#pragma unroll
        for (int c = 0; c < 4; ++c)
            wreg[4 * s + c] = W[(size_t)((g << 6) + (e << 2) + c) * NH + h];
    }
    const float bb = bias[h];

    char* myLds = &lds[wid * 8192];
    const int gwave = blockIdx.x * 4 + wid;
    const int nwaves = gridDim.x * 4;          // 8192
    const int stride = nwaves * 2;             // 16384 positions per round

    const size_t laneOff = (size_t)lane * 4;   // float offset for staging
    const int qkByte = (g < 4) ? 0 : 2048;     // q half vs k half of buffer
    const int chunkByte = (g & 3) * 256;       // 64-float chunk within row

    const int p0 = gwave * 2;
    // prologue: stage tile p0 into buffer 0
    stage16(q + (size_t)p0 * 256 + laneOff,       myLds + 0);
    stage16(q + (size_t)(p0 + 1) * 256 + laneOff, myLds + 1024);
    stage16(k + (size_t)p0 * 256 + laneOff,       myLds + 2048);
    stage16(k + (size_t)(p0 + 1) * 256 + laneOff, myLds + 3072);

    int buf = 0;
    for (int p = p0; p < NPOS; p += stride) {
        const int pn = p + stride;
        if (pn < NPOS) {
            char* nb = myLds + ((buf ^ 1) << 12);
            stage16(q + (size_t)pn * 256 + laneOff,       nb + 0);
            stage16(q + (size_t)(pn + 1) * 256 + laneOff, nb + 1024);
            stage16(k + (size_t)pn * 256 + laneOff,       nb + 2048);
            stage16(k + (size_t)(pn + 1) * 256 + laneOff, nb + 3072);
            // wait for CURRENT buffer's 4 loads (oldest); next tile's 4 stay
            // in flight (also drains prev iter's 2 tiny stores -- harmless)
            asm volatile("s_waitcnt vmcnt(4)" ::: "memory");
        } else {
            asm volatile("s_waitcnt vmcnt(0)" ::: "memory");
        }

        // A0: 256B-aligned base + g*16; step address = A0 ^ (s<<4)
        const uintptr_t A0 =
            (uintptr_t)(myLds + (buf << 12) + qkByte + chunkByte) + (g << 4);
        float acc0 = 0.f, acc1 = 0.f;
#pragma unroll
        for (int s = 0; s < 16; ++s) {
            const float* f0 = (const float*)(A0 ^ (uintptr_t)(s << 4));
            f32x4 v0 = *(const f32x4*)(f0);         // pos p   (ds_read_b128)
            f32x4 v1 = *(const f32x4*)(f0 + 256);   // pos p+1 (+1024B imm)
            acc0 += v0.x * wreg[4 * s + 0];
            acc0 += v0.y * wreg[4 * s + 1];
            acc0 += v0.z * wreg[4 * s + 2];
            acc0 += v0.w * wreg[4 * s + 3];
            acc1 += v1.x * wreg[4 * s + 0];
            acc1 += v1.y * wreg[4 * s + 1];
            acc1 += v1.z * wreg[4 * s + 2];
            acc1 += v1.w * wreg[4 * s + 3];
        }
        acc0 += __shfl_xor(acc0, 8);
        acc0 += __shfl_xor(acc0, 16);
        acc0 += __shfl_xor(acc0, 32);
        acc1 += __shfl_xor(acc1, 8);
        acc1 += __shfl_xor(acc1, 16);
        acc1 += __shfl_xor(acc1, 32);
        if (lane < 8) {
            attn[(size_t)p * NH + lane]       = 1.f / (1.f + __expf(-(acc0 + bb)));
            attn[(size_t)(p + 1) * NH + lane] = 1.f / (1.f + __expf(-(acc1 + bb)));
        }
        buf ^= 1;
    }
}

// ---------------------------------------------------------------------------
// Kernel 2: dim2_mask union of top-k / bottom-k indices (exact rank count,
// matches jax.lax.top_k stable tie-breaking). Register-accumulated selection,
// ballot + 2 atomicOr per wave; 64 publisher blocks seed the mask per-task;
// everyone early-exits on full mask via volatile loads (monotonic bits =>
// stale reads are safe).
// ---------------------------------------------------------------------------
__global__ __launch_bounds__(256) void topk_kernel(
    const float* __restrict__ attn, const float* __restrict__ m1,
    const float* __restrict__ m2, unsigned int* __restrict__ maskw)
{
    __shared__ __align__(16) float a[NN];
    __shared__ int snotfull;
    const int tid = threadIdx.x;
    const int T = 2 * NB * NN * NH;   // 16384 tasks
    const bool publisher = (blockIdx.x < 64);
    const volatile unsigned int* vmask = maskw;
    bool selAcc = false;
    bool broke = false;

    for (int t = blockIdx.x; t < T; t += gridDim.x) {
        if (t != (int)blockIdx.x) {
            if (tid == 0) snotfull = 0;
            __syncthreads();
            if (tid < 8 && vmask[tid] != 0xFFFFFFFFu) snotfull = 1;
            __syncthreads();
            if (!snotfull) { broke = true; break; }
        }

        const int variant = t >> 13;
        const int r = t & 8191;
        const int h = r & 7;
        const int n = (r >> 3) & 255;
        const int b = r >> 11;
        const size_t rowBase = ((size_t)(b * NN + n)) * NN;
        const float* mk = variant ? m2 : m1;
        const int kt = variant ? 128 : 64;
        const int kb = 64;

        a[tid] = attn[(rowBase + tid) * NH + h] * mk[rowBase + tid];
        __syncthreads();

        const float av = a[tid];
        int gt = 0, lt = 0, el = 0;
#pragma unroll 8
        for (int u4 = 0; u4 < NN / 4; ++u4) {
            const f32x4 w = *reinterpret_cast<const f32x4*>(&a[u4 * 4]);
            const int u = u4 * 4;
            gt += (w.x > av) + (w.y > av) + (w.z > av) + (w.w > av);
            lt += (w.x < av) + (w.y < av) + (w.z < av) + (w.w < av);
            el += ((w.x == av) & (u + 0 < tid)) + ((w.y == av) & (u + 1 < tid))
                + ((w.z == av) & (u + 2 < tid)) + ((w.w == av) & (u + 3 < tid));
        }
        const bool sel = ((gt + el) < kt) || ((lt + el) < kb);
        selAcc |= sel;

        if (publisher) {
            const unsigned long long bal = __ballot(sel);
            if ((tid & 63) == 0) {
                const int w = tid >> 6;
                atomicOr(&maskw[w * 2 + 0], (unsigned int)(bal & 0xFFFFFFFFull));
                atomicOr(&maskw[w * 2 + 1], (unsigned int)(bal >> 32));
            }
        }
        __syncthreads();
    }

    if (!broke && !publisher) {
        const unsigned long long bal = __ballot(selAcc);
        if ((tid & 63) == 0) {
            const int w = tid >> 6;
            atomicOr(&maskw[w * 2 + 0], (unsigned int)(bal & 0xFFFFFFFFull));
            atomicOr(&maskw[w * 2 + 1], (unsigned int)(bal >> 32));
        }
    }
}

// ---------------------------------------------------------------------------
// Kernel 3: out *= (m1+m2) * dim2_mask[m], in place, float4 over H.
// ---------------------------------------------------------------------------
__global__ __launch_bounds__(256) void finalize_kernel(
    float* __restrict__ out, const float* __restrict__ m1,
    const float* __restrict__ m2, const unsigned int* __restrict__ maskw)
{
    const int total = NPOS * 2;       // float4 units (H=8 -> 2 per position)
    for (int i4 = blockIdx.x * blockDim.x + threadIdx.x; i4 < total;
         i4 += gridDim.x * blockDim.x) {
        const int m = (i4 >> 1) & 255;
        const int bn = i4 >> 9;
        const float bit = ((maskw[m >> 5] >> (m & 31)) & 1u) ? 1.f : 0.f;
        const size_t mi = (size_t)bn * NN + m;
        const float scale = (m1[mi] + m2[mi]) * bit;
        f32x4 v = reinterpret_cast<f32x4*>(out)[i4];
        v.x *= scale; v.y *= scale; v.z *= scale; v.w *= scale;
        reinterpret_cast<f32x4*>(out)[i4] = v;
    }
}

__global__ void init_kernel(unsigned int* maskw)
{
    if (threadIdx.x < 8) maskw[threadIdx.x] = 0u;
}

extern "C" void kernel_launch(void* const* d_in, const int* in_sizes, int n_in,
                              void* d_out, int out_size, void* d_ws, size_t ws_size,
                              hipStream_t stream) {
    const float* q    = (const float*)d_in[0];
    const float* kk   = (const float*)d_in[1];
    const float* m1   = (const float*)d_in[2];
    const float* m2   = (const float*)d_in[3];
    const float* W    = (const float*)d_in[4];
    const float* bias = (const float*)d_in[5];
    float* out = (float*)d_out;

    unsigned int* maskw = (unsigned int*)d_ws;

    hipLaunchKernelGGL(init_kernel, dim3(1), dim3(64), 0, stream, maskw);
    // 2048 blocks * 4 waves = 8192 waves; stride 16384 -> exactly 16 tiles/wave
    hipLaunchKernelGGL(attn_kernel, dim3(2048), dim3(256), 0, stream,
                       q, kk, W, bias, out);
    hipLaunchKernelGGL(topk_kernel, dim3(1024), dim3(256), 0, stream,
                       out, m1, m2, maskw);
    hipLaunchKernelGGL(finalize_kernel, dim3(2048), dim3(256), 0, stream,
                       out, m1, m2, maskw);
}